// Round 9
// baseline (629.599 us; speedup 1.0000x reference)
//
#include <hip/hip_runtime.h>
#include <stdint.h>

#define B_TOTAL 4096
#define T_STEPS 512
#define IN_DIM 16
#define H1 5
#define H2 50
#define NCLS 20
#define XFS 40           // xf row stride in shorts

typedef __attribute__((ext_vector_type(8))) short bf16x8;
typedef __attribute__((ext_vector_type(4))) float f32x4;

#define LOG2E 1.44269504f
#define C2L   2.88539008f   /* 2*log2(e) */

// Fused cell update, 8 transcendentals (5 exp2 + 3 rcp):
//   sigma(i)*tanhs(g) = C2L*(Eg-1)*rcp((1+Ei)(1+Eg))
//   sigma(o)*tanhs(c) = (Ec-1)*rcp((1+Eo)(1+Ec))
// (weights pre-scaled: i,f,o by LOG2E; g by 2LOG2E; cst pre-scaled by 2LOG2E)
#define CELL_UPDATE(A0_,A1_,A2_,A3_,CST_,H_) do { \
    float Ei_ = __builtin_amdgcn_exp2f(-(A0_)); \
    float Ef_ = __builtin_amdgcn_exp2f(-(A1_)); \
    float Eg_ = __builtin_amdgcn_exp2f( (A2_)); \
    float Eo_ = __builtin_amdgcn_exp2f(-(A3_)); \
    float gf_ = __builtin_amdgcn_rcpf(1.0f + Ef_); \
    float R1_ = __builtin_amdgcn_rcpf((1.0f + Ei_) * (1.0f + Eg_)); \
    float s1_ = fmaf(C2L, Eg_, -C2L); \
    CST_ = fmaf(gf_, CST_, s1_ * R1_); \
    float Ec_ = __builtin_amdgcn_exp2f(CST_); \
    float R2_ = __builtin_amdgcn_rcpf((1.0f + Eo_) * (1.0f + Ec_)); \
    H_ = (Ec_ - 1.0f) * R2_; \
  } while(0)

// dword = [top16(a) | top16(b)]  (memory shorts: [0]=b, [1]=a)
__device__ inline unsigned pack_top(float a, float b){
  return __builtin_amdgcn_perm(__float_as_uint(a), __float_as_uint(b), 0x07060302u);
}
__device__ inline void cvt_store(unsigned short* dh, unsigned short* dl, float4 v){
  uint2 H, L;
  H.x = pack_top(v.y, v.x);
  H.y = pack_top(v.w, v.z);
  float r0 = v.x - __uint_as_float(__float_as_uint(v.x) & 0xFFFF0000u);
  float r1 = v.y - __uint_as_float(__float_as_uint(v.y) & 0xFFFF0000u);
  float r2 = v.z - __uint_as_float(__float_as_uint(v.z) & 0xFFFF0000u);
  float r3 = v.w - __uint_as_float(__float_as_uint(v.w) & 0xFFFF0000u);
  L.x = pack_top(r1, r0);
  L.y = pack_top(r3, r2);
  *(uint2*)dh = H; *(uint2*)dl = L;
}
__device__ inline void split1(float h, unsigned short& hi, unsigned short& lo){
  unsigned u = __float_as_uint(h);
  hi = (unsigned short)(u >> 16);
  float r = h - __uint_as_float(u & 0xFFFF0000u);
  lo = (unsigned short)(__float_as_uint(r) >> 16);
}
__device__ inline void wsplit(float w, short& hi, short& lo){
  unsigned u = __float_as_uint(w);
  hi = (short)(u >> 16);
  float r = w - __uint_as_float(u & 0xFFFF0000u);
  lo = (short)(__float_as_uint(r) >> 16);
}
// split 8 floats into hi/lo bf16x8 fragments (peel only)
__device__ inline void xsplit(float4 a, float4 b, bf16x8& H, bf16x8& L){
  short h,l;
  wsplit(a.x,h,l); H[0]=h; L[0]=l;
  wsplit(a.y,h,l); H[1]=h; L[1]=l;
  wsplit(a.z,h,l); H[2]=h; L[2]=l;
  wsplit(a.w,h,l); H[3]=h; L[3]=l;
  wsplit(b.x,h,l); H[4]=h; L[4]=l;
  wsplit(b.y,h,l); H[5]=h; L[5]=l;
  wsplit(b.z,h,l); H[6]=h; L[6]=l;
  wsplit(b.w,h,l); H[7]=h; L[7]=l;
}

#define LDS_FENCE() __asm__ volatile("s_waitcnt lgkmcnt(0)" ::: "memory")
#define BARRIER()   __asm__ volatile("s_barrier" ::: "memory")

// Fused 2-layer LSTM + FC. grid 256 (16-batch tiles), block 512 (8 waves,
// 2/SIMD). GATE-SPLIT: SIMD s hosts waves s (gates i,f + act + state) and
// s+4 (gates g,o -> f32 preacts via LDS). Rationale (R3 vs R7 A/B): two
// CO-RESIDENT waves fill each other's stalls (R3: 2 streams in 1.25x); a
// single wave's in-stream ILP does not (R7: 1.94x). Splitting the stream
// across 2 waves/SIMD keeps per-SIMD issue constant (~480cy) but lets the
// HW scheduler overlap the ~600cy of per-wave dep-latency bubbles.
// Two raw barriers/step: [barA] phase1: all waves MFMA their 2 gates
// (uppers write pre[2][4][64] f32x4) [barB] phase2: lower waves read g,o
// preacts, act, write h to a2; wave 4 produces the x bf16 ring (its idle
// phase). Exchange is exact f32 -> numerics bit-identical to R8 (472us).
// Column tiles as before: tiles 0-2 = lstm2 cells 16t..16t+15; tile 3 =
// cells 48,49 (l15<2) + lstm1 cells 0..4 (l15 2..6), with x chunk2.
__global__ __launch_bounds__(512, 1) void lstm_fused_kernel(
    const float* __restrict__ x,
    const float* __restrict__ w_ih1, const float* __restrict__ w_hh1,
    const float* __restrict__ b_ih1, const float* __restrict__ b_hh1,
    const float* __restrict__ w_ih2, const float* __restrict__ w_hh2,
    const float* __restrict__ b_ih2, const float* __restrict__ b_hh2,
    const float* __restrict__ fc_w, const float* __restrict__ fc_b,
    float* __restrict__ out)
{
  const int tid  = threadIdx.x;
  const int lane = tid & 63;
  const int wave = tid >> 6;      // 0..7
  const int tile = wave & 3;      // column tile 0..3
  const bool upper = wave >= 4;   // gates g,o producer
  const int l15  = lane & 15;
  const int quad = lane >> 4;
  const int b0   = blockIdx.x * 16;

  // a2[buf][batch16][col72]: h2 0-49 | h1 50-54 | zero 55-63 | pad 64-71
  __shared__ __align__(16) unsigned short a2h[2][16*72], a2l[2][16*72];
  // x fragment ring: [slot2][batch16][k XFS]
  __shared__ __align__(16) unsigned short xfh[2][16*XFS], xfl[2][16*XFS];
  // gate preact exchange: pre[gate(g=0,o=1)][tile][lane] = f32x4
  __shared__ __align__(16) float pre[2][4][64][4];
  __shared__ float h2f[16*52];

  const bf16x8 zero8 = {0,0,0,0,0,0,0,0};
  const f32x4  zero4 = {0.f,0.f,0.f,0.f};

  bf16x8 Bh[2][3], Bl[2][3];      // 2 gates per wave
  f32x4 biasv[2];
  float cst[4] = {0.f,0.f,0.f,0.f};   // c-state (lower waves only)

  // bank swizzle terms (R6): reads keyed by batch=l15, writes keyed by row
  const int rsw = ((l15 >> 3) & 1) << 3;
  const int wsw = (quad >> 1) << 3;

#pragma unroll
  for (int t=0; t<2; ++t)
#pragma unroll
    for (int kt=0; kt<3; ++kt){ Bh[t][kt]=zero8; Bl[t][kt]=zero8; }

  // ---- weights: this wave's 2 gates (lower: i,f = 0,1; upper: g,o = 2,3) ----
#pragma unroll
  for (int t=0; t<2; ++t){
    const int gg = (upper ? 2 : 0) + t;
    const float gsc = (gg == 2) ? C2L : LOG2E;
    float bias = 0.f;
    if (tile < 3){
      const int c = tile*16 + l15;
      const int grow = gg*H2 + c;
#pragma unroll
      for (int kt=0; kt<2; ++kt){
#pragma unroll
        for (int j=0;j<8;j++){
          const int kk = kt*32 + quad*8 + j;
          float w = 0.f;
          if (kk < H2)         w = w_hh2[grow*H2 + kk];
          else if (kk < H2+H1) w = w_ih2[grow*H1 + (kk-H2)];
          w *= gsc;
          short hi, lo; wsplit(w, hi, lo);
          Bh[t][kt][j] = hi; Bl[t][kt][j] = lo;
        }
      }
      bias = gsc * (b_ih2[grow] + b_hh2[grow]);
    } else if (l15 < 2){
      const int grow = gg*H2 + 48 + l15;
#pragma unroll
      for (int kt=0; kt<2; ++kt){
#pragma unroll
        for (int j=0;j<8;j++){
          const int kk = kt*32 + quad*8 + j;
          float w = 0.f;
          if (kk < H2)         w = w_hh2[grow*H2 + kk];
          else if (kk < H2+H1) w = w_ih2[grow*H1 + (kk-H2)];
          w *= gsc;
          short hi, lo; wsplit(w, hi, lo);
          Bh[t][kt][j] = hi; Bl[t][kt][j] = lo;
        }
      }
      bias = gsc * (b_ih2[grow] + b_hh2[grow]);
    } else if (l15 < 7){
      const int e = l15 - 2;
      const int grow = gg*H1 + e;
#pragma unroll
      for (int j=0;j<8;j++){
        const int kk = 32 + quad*8 + j;   // chunk1 global k (h1 at 50..54)
        float w1 = (kk >= H2 && kk < H2+H1) ? gsc * w_hh1[grow*H1 + (kk-H2)] : 0.f;
        short hi, lo; wsplit(w1, hi, lo);
        Bh[t][1][j] = hi; Bl[t][1][j] = lo;
        const int k2 = quad*8 + j;        // chunk2 k (x dims)
        float w2 = (k2 < IN_DIM) ? gsc * w_ih1[grow*IN_DIM + k2] : 0.f;
        wsplit(w2, hi, lo);
        Bh[t][2][j] = hi; Bl[t][2][j] = lo;
      }
      bias = gsc * (b_ih1[grow] + b_hh1[grow]);
    }
    biasv[t][0]=bias; biasv[t][1]=bias; biasv[t][2]=bias; biasv[t][3]=bias;
  }

  // ---- zero LDS state ----
  { unsigned short* p = &a2h[0][0]; for (int i=tid;i<2*16*72;i+=512)  p[i]=0; }
  { unsigned short* p = &a2l[0][0]; for (int i=tid;i<2*16*72;i+=512)  p[i]=0; }
  { unsigned short* p = &xfh[0][0]; for (int i=tid;i<2*16*XFS;i+=512) p[i]=0; }
  { unsigned short* p = &xfl[0][0]; for (int i=tid;i<2*16*XFS;i+=512) p[i]=0; }
  __syncthreads();

  // ---- x producer: wave 4 (idle in phase 2) ----
  const bool xprod = (wave == 4);
  const int pxb = lane >> 2;
  const int pxd = (lane & 3) * 4;
  const float* pxbase = &x[(size_t)(b0+pxb)*T_STEPS*IN_DIM + pxd];
  float4 PA, PB;
  if (xprod){
    float4 v1 = *(const float4*)(pxbase + 1*IN_DIM);     // x(1) -> slot 1
    cvt_store(&xfh[1][pxb*XFS+pxd], &xfl[1][pxb*XFS+pxd], v1);
    PA = *(const float4*)(pxbase + 2*IN_DIM);            // x(2), written at T=0
  }

  // ---- peel: waves 3 & 7 compute h1(0) from x(0) into a2[0] ----
  f32x4 pacc0 = zero4, pacc1 = zero4;
  if (tile == 3){
    bf16x8 XAh = zero8, XAl = zero8;
    if (quad < 2){
      const float* xp = &x[(size_t)(b0+l15)*T_STEPS*IN_DIM + quad*8];
      xsplit(*(const float4*)xp, *(const float4*)(xp+4), XAh, XAl);
    }
#pragma unroll
    for (int t=0; t<2; ++t){
      f32x4 c2 = __builtin_amdgcn_mfma_f32_16x16x32_bf16(XAh, Bh[t][2], biasv[t], 0,0,0);
      c2 = __builtin_amdgcn_mfma_f32_16x16x32_bf16(XAl, Bh[t][2], c2, 0,0,0);
      c2 = __builtin_amdgcn_mfma_f32_16x16x32_bf16(XAh, Bl[t][2], c2, 0,0,0);
      if (t == 0) pacc0 = c2; else pacc1 = c2;
    }
    if (upper){
      *(f32x4*)&pre[0][3][lane][0] = pacc0;
      *(f32x4*)&pre[1][3][lane][0] = pacc1;
    }
  }
  LDS_FENCE(); BARRIER();
  if (tile == 3 && !upper){
    f32x4 g4 = *(const f32x4*)&pre[0][3][lane][0];
    f32x4 o4 = *(const f32x4*)&pre[1][3][lane][0];
    const bool isl1 = (l15 >= 2) && (l15 < 7);
#pragma unroll
    for (int r=0;r<4;r++){
      float cpre = cst[r], h;
      CELL_UPDATE(pacc0[r], pacc1[r], g4[r], o4[r], cpre, h);
      if (isl1){
        cst[r] = cpre;
        unsigned short hh, hl; split1(h, hh, hl);
        const int row = quad*4 + r;
        a2h[0][row*72 + ((48 + l15) ^ wsw)] = hh;
        a2l[0][row*72 + ((48 + l15) ^ wsw)] = hl;
      }
    }
  }
  LDS_FENCE(); BARRIER();

#define MAIN_BODY(T_, RD_, WR_, PXW_, PXL_, LAST_) do { \
    /* ---- phase 1: MFMA both gates ---- */ \
    const int rb_ = l15*72; \
    bf16x8 ah0 = *(const bf16x8*)&a2h[RD_][rb_ +      ((quad*8) ^ rsw)]; \
    bf16x8 al0 = *(const bf16x8*)&a2l[RD_][rb_ +      ((quad*8) ^ rsw)]; \
    bf16x8 ah1 = *(const bf16x8*)&a2h[RD_][rb_ + 32 + ((quad*8) ^ rsw)]; \
    bf16x8 al1 = *(const bf16x8*)&a2l[RD_][rb_ + 32 + ((quad*8) ^ rsw)]; \
    bf16x8 xH = zero8, xL = zero8; \
    if (tile == 3){ \
      xH = *(const bf16x8*)&xfh[WR_][l15*XFS + quad*8]; \
      xL = *(const bf16x8*)&xfl[WR_][l15*XFS + quad*8]; \
    } \
    f32x4 acc0, acc1; \
    _Pragma("unroll") \
    for (int t=0; t<2; ++t){ \
      f32x4 c0 = __builtin_amdgcn_mfma_f32_16x16x32_bf16(ah0, Bh[t][0], biasv[t], 0,0,0); \
      c0 = __builtin_amdgcn_mfma_f32_16x16x32_bf16(al0, Bh[t][0], c0, 0,0,0); \
      c0 = __builtin_amdgcn_mfma_f32_16x16x32_bf16(ah0, Bl[t][0], c0, 0,0,0); \
      f32x4 c1 = __builtin_amdgcn_mfma_f32_16x16x32_bf16(ah1, Bh[t][1], zero4, 0,0,0); \
      c1 = __builtin_amdgcn_mfma_f32_16x16x32_bf16(al1, Bh[t][1], c1, 0,0,0); \
      c1 = __builtin_amdgcn_mfma_f32_16x16x32_bf16(ah1, Bl[t][1], c1, 0,0,0); \
      f32x4 s_; \
      if (tile == 3){ \
        f32x4 c2 = __builtin_amdgcn_mfma_f32_16x16x32_bf16(xH, Bh[t][2], zero4, 0,0,0); \
        c2 = __builtin_amdgcn_mfma_f32_16x16x32_bf16(xL, Bh[t][2], c2, 0,0,0); \
        c2 = __builtin_amdgcn_mfma_f32_16x16x32_bf16(xH, Bl[t][2], c2, 0,0,0); \
        s_ = (c0 + c1) + c2; \
      } else s_ = c0 + c1; \
      if (t == 0) acc0 = s_; else acc1 = s_; \
    } \
    if (upper){ \
      *(f32x4*)&pre[0][tile][lane][0] = acc0; \
      *(f32x4*)&pre[1][tile][lane][0] = acc1; \
    } \
    LDS_FENCE(); BARRIER();   /* preacts published */ \
    /* ---- phase 2: act (lower) / x production (wave 4) ---- */ \
    if (!upper){ \
      f32x4 g4 = *(const f32x4*)&pre[0][tile][lane][0]; \
      f32x4 o4 = *(const f32x4*)&pre[1][tile][lane][0]; \
      if (tile < 3){ \
        const int wrb = quad*4*72 + ((tile*16 + l15) ^ wsw); \
        _Pragma("unroll") \
        for (int r=0;r<4;r++){ \
          float h; \
          CELL_UPDATE(acc0[r], acc1[r], g4[r], o4[r], cst[r], h); \
          unsigned short hh, hl; split1(h, hh, hl); \
          a2h[WR_][wrb + r*72] = hh; \
          a2l[WR_][wrb + r*72] = hl; \
          if (LAST_){ \
            out[(size_t)B_TOTAL*NCLS + (size_t)(b0+quad*4+r)*H2 + tile*16+l15] = h; \
            h2f[(quad*4+r)*52 + tile*16+l15] = h; \
          } \
        } \
      } else { \
        const int wrb = quad*4*72 + ((48 + l15) ^ wsw); \
        const bool wv_ = l15 < 7; \
        _Pragma("unroll") \
        for (int r=0;r<4;r++){ \
          float h; \
          CELL_UPDATE(acc0[r], acc1[r], g4[r], o4[r], cst[r], h); \
          if (wv_){ \
            unsigned short hh, hl; split1(h, hh, hl); \
            a2h[WR_][wrb + r*72] = hh; \
            a2l[WR_][wrb + r*72] = hl; \
            if (LAST_ && l15 < 2){ \
              out[(size_t)B_TOTAL*NCLS + (size_t)(b0+quad*4+r)*H2 + 48+l15] = h; \
              h2f[(quad*4+r)*52 + 48+l15] = h; \
            } \
          } \
        } \
      } \
    } else if (xprod){ \
      cvt_store(&xfh[RD_][pxb*XFS+pxd], &xfl[RD_][pxb*XFS+pxd], PXW_); /* x(T+2) */ \
      const int nidx_ = ((T_)+3 < T_STEPS) ? (T_)+3 : T_STEPS-1; \
      PXL_ = *(const float4*)(pxbase + (size_t)nidx_*IN_DIM);          /* x(T+3) */ \
    } \
    LDS_FENCE(); BARRIER();   /* h(t) published */ \
  } while(0)

  // main loop, unrolled x2 (compile-time parity), last pair peeled.
  for (int t2 = 0; t2 < T_STEPS-2; t2 += 2){
    MAIN_BODY(t2,   0, 1, PA, PB, 0);
    MAIN_BODY(t2+1, 1, 0, PB, PA, 0);
  }
  MAIN_BODY(T_STEPS-2, 0, 1, PA, PB, 0);
  MAIN_BODY(T_STEPS-1, 1, 0, PB, PA, 1);

#undef MAIN_BODY

  __syncthreads();
  // fused FC: 16 batches x 20 outputs = 320 results on 512 threads
  for (int i = tid; i < 16*NCLS; i += 512){
    const int b = i / NCLS, o = i % NCLS;
    float s = fc_b[o];
#pragma unroll 10
    for (int k=0;k<H2;k++) s += fc_w[o*H2+k] * h2f[b*52+k];
    out[(size_t)(b0+b)*NCLS + o] = s;
  }
}

extern "C" void kernel_launch(void* const* d_in, const int* in_sizes, int n_in,
                              void* d_out, int out_size, void* d_ws, size_t ws_size,
                              hipStream_t stream) {
  const float* x     = (const float*)d_in[0];
  const float* w_ih1 = (const float*)d_in[1];
  const float* w_hh1 = (const float*)d_in[2];
  const float* b_ih1 = (const float*)d_in[3];
  const float* b_hh1 = (const float*)d_in[4];
  const float* w_ih2 = (const float*)d_in[5];
  const float* w_hh2 = (const float*)d_in[6];
  const float* b_ih2 = (const float*)d_in[7];
  const float* b_hh2 = (const float*)d_in[8];
  const float* fc_w  = (const float*)d_in[9];
  const float* fc_b  = (const float*)d_in[10];
  float* out = (float*)d_out;

  lstm_fused_kernel<<<dim3(B_TOTAL/16), dim3(512), 0, stream>>>(
      x, w_ih1, w_hh1, b_ih1, b_hh1, w_ih2, w_hh2, b_ih2, b_hh2, fc_w, fc_b, out);
}